// Round 6
// baseline (193.533 us; speedup 1.0000x reference)
//
#include <hip/hip_runtime.h>

#define BATCH 16
#define NANCH 8400
#define MGT 32
#define NCLS 80
#define RCH 64
#define NCH 144
#define TOPKK 10
#define MAXC 576    // max in-box candidate cells: <=19^2 + 11^2 + 7^2 = 531
#define PBLK 2100   // pbox blocks: 525 * 4 sides
#define TKB 512     // topk blocks
#define BCEB 2625   // bce blocks
#define FINB 525    // final blocks

struct AInfo { int lvl, pos, W, HW; float s, ax, ay; };

__device__ __forceinline__ AInfo anchor_of(int n) {
  AInfo a;
  if (n < 6400)      { a.lvl = 0; a.pos = n;        a.W = 80; a.HW = 6400; a.s = 8.f;  }
  else if (n < 8000) { a.lvl = 1; a.pos = n - 6400; a.W = 40; a.HW = 1600; a.s = 16.f; }
  else               { a.lvl = 2; a.pos = n - 8000; a.W = 20; a.HW = 400;  a.s = 32.f; }
  int px = a.pos % a.W, py = a.pos / a.W;
  a.ax = (px + 0.5f) * a.s;
  a.ay = (py + 0.5f) * a.s;
  return a;
}

__device__ __forceinline__ const float* lvl_ptr(const float* p0, const float* p1,
                                                const float* p2, int lvl) {
  return lvl == 0 ? p0 : (lvl == 1 ? p1 : p2);
}

__device__ __forceinline__ float iou_xyxy(float4 a, float4 b) {
  float ix = fmaxf(fminf(a.z, b.z) - fmaxf(a.x, b.x), 0.f);
  float iy = fmaxf(fminf(a.w, b.w) - fmaxf(a.y, b.y), 0.f);
  float inter = ix * iy;
  float w1 = fmaxf(a.z - a.x, 0.f), h1 = fmaxf(a.w - a.y, 0.f);
  float w2 = fmaxf(b.z - b.x, 0.f), h2 = fmaxf(b.w - b.y, 0.f);
  float uni = w1 * h1 + w2 * h2 - inter + 1e-7f;
  return inter / uni;
}

__device__ __forceinline__ float ciou_xyxy(float4 a, float4 b) {
  const float eps = 1e-7f;
  float ix = fmaxf(fminf(a.z, b.z) - fmaxf(a.x, b.x), 0.f);
  float iy = fmaxf(fminf(a.w, b.w) - fmaxf(a.y, b.y), 0.f);
  float inter = ix * iy;
  float w1 = fmaxf(a.z - a.x, 0.f), h1 = fmaxf(a.w - a.y, 0.f);
  float w2 = fmaxf(b.z - b.x, 0.f), h2 = fmaxf(b.w - b.y, 0.f);
  float uni = w1 * h1 + w2 * h2 - inter + eps;
  float iou = inter / uni;
  float cx1 = (a.x + a.z) * 0.5f, cy1 = (a.y + a.w) * 0.5f;
  float cx2 = (b.x + b.z) * 0.5f, cy2 = (b.y + b.w) * 0.5f;
  float rho2 = (cx2 - cx1) * (cx2 - cx1) + (cy2 - cy1) * (cy2 - cy1);
  float cw = fmaxf(a.z, b.z) - fminf(a.x, b.x);
  float ch = fmaxf(a.w, b.w) - fminf(a.y, b.y);
  float c2 = cw * cw + ch * ch + eps;
  const float kpi = 4.f / (float)(M_PI * M_PI);
  float dat = atanf(w2 / (h2 + eps)) - atanf(w1 / (h1 + eps));
  float v = kpi * dat * dat;
  float alpha = v / (1.f - iou + v + eps);
  return iou - (rho2 / c2 + alpha * v);
}

__device__ __forceinline__ float block_sum256(float v) {
  __shared__ float sm[4];
  #pragma unroll
  for (int off = 32; off; off >>= 1) v += __shfl_xor(v, off);
  __syncthreads();
  if ((threadIdx.x & 63) == 0) sm[threadIdx.x >> 6] = v;
  __syncthreads();
  return (threadIdx.x == 0) ? (sm[0] + sm[1] + sm[2] + sm[3]) : 0.f;
}

// --- K1: box decode + logZ cache + slots/accum/counter init ----------------
__global__ __launch_bounds__(256) void k_pre(
    const float* __restrict__ p0, const float* __restrict__ p1, const float* __restrict__ p2,
    float* __restrict__ pboxf, float* __restrict__ logz,
    unsigned long long* __restrict__ slots, double* __restrict__ accum,
    int* __restrict__ counter) {
  int blk = blockIdx.x, tid = threadIdx.x;
  if (blk == 0) {
    if (tid < 8) accum[tid] = 0.0;
    if (tid == 8) *counter = 0;
  }
  // one thread per (anchor, side)
  int q = blk & 3;
  int i = (blk >> 2) * 256 + tid;            // 0 .. 134399
  int b = i / NANCH, n = i % NANCH;
  AInfo A = anchor_of(n);
  const float* p = lvl_ptr(p0, p1, p2, A.lvl);
  size_t base = (size_t)b * NCH * A.HW + A.pos;

  float z[16]; float zm = -1e30f;
  #pragma unroll
  for (int j = 0; j < 16; ++j) {
    z[j] = p[base + (size_t)(q * 16 + j) * A.HW];
    zm = fmaxf(zm, z[j]);
  }
  float se = 0.f, ae = 0.f;
  #pragma unroll
  for (int j = 0; j < 16; ++j) {
    float e = __expf(z[j] - zm);
    se += e; ae += e * (float)j;
  }
  float d = ae / se * A.s;
  float val = (q == 0) ? A.ax - d : (q == 1) ? A.ay - d : (q == 2) ? A.ax + d : A.ay + d;
  pboxf[(size_t)i * 4 + q] = val;
  logz[(size_t)i * 4 + q] = zm + __logf(se);   // log-softmax denominator (raw logits)
  if (q == 0) slots[i] = 0ULL;
}

// --- K2: topk (512 blocks) + BCE base stream (2625 blocks), co-scheduled ---
__global__ __launch_bounds__(256) void k_mid(
    const float* __restrict__ p0, const float* __restrict__ p1, const float* __restrict__ p2,
    const float4* __restrict__ pbox, const float* __restrict__ gtb, const int* __restrict__ gtl,
    float* __restrict__ metric_max, unsigned long long* __restrict__ slots,
    double* __restrict__ accum) {
  __shared__ float val[MAXC];
  __shared__ int   idx[MAXC];
  __shared__ float cio[MAXC];
  __shared__ float rv[4];
  __shared__ int   ri[4], rs[4], sdone[1];
  int blk = blockIdx.x, tid = threadIdx.x;

  if (blk >= TKB) {
    // --- BCE base term: contiguous float4 stream over cls planes ---
    int r = blk - TKB;                       // 0 .. 2624
    int i = r * 256 + tid;                   // 0 .. 671999
    float lb = 0.f;
    #pragma unroll
    for (int j = 0; j < 4; ++j) {
      int u = i + j * 672000;                // < 2688000
      int b = u / 168000;
      int rr = u % 168000;
      const float4* src;
      if (rr < 128000)      src = (const float4*)p0 + ((size_t)(b * NCH + RCH) * 1600 + rr);
      else if (rr < 160000) src = (const float4*)p1 + ((size_t)(b * NCH + RCH) * 400 + (rr - 128000));
      else                  src = (const float4*)p2 + ((size_t)(b * NCH + RCH) * 100 + (rr - 160000));
      float4 z4 = *src;
      lb += fmaxf(z4.x, 0.f) + __logf(1.f + __expf(-fabsf(z4.x)));
      lb += fmaxf(z4.y, 0.f) + __logf(1.f + __expf(-fabsf(z4.y)));
      lb += fmaxf(z4.z, 0.f) + __logf(1.f + __expf(-fabsf(z4.z)));
      lb += fmaxf(z4.w, 0.f) + __logf(1.f + __expf(-fabsf(z4.w)));
    }
    float tot = block_sum256(lb);
    if (tid == 0) atomicAdd(&accum[0], (double)tot);
    return;
  }

  // --- topk for one (b, gt) ---
  int b = blk >> 5, m = blk & 31;
  float4 g = ((const float4*)gtb)[b * MGT + m];
  int gl = min(max(gtl[b * MGT + m], 0), NCLS - 1);

  const int   Ws[3] = {80, 40, 20};
  const float ss[3] = {8.f, 16.f, 32.f};
  const int   nb[3] = {0, 6400, 8000};
  int x0[3], y0[3], nxl[3], cb[3];
  int cnt = 0;
  #pragma unroll
  for (int L = 0; L < 3; ++L) {
    float s = ss[L]; int W = Ws[L];
    int ax0 = max((int)floorf(g.x / s - 0.5f), 0);        // widened 1 low side
    int ax1 = min((int)ceilf (g.z / s - 0.5f), W - 1);    // widened 1 high side
    int ay0 = max((int)floorf(g.y / s - 0.5f), 0);
    int ay1 = min((int)ceilf (g.w / s - 0.5f), W - 1);
    int nx = max(ax1 - ax0 + 1, 0);
    int ny = max(ay1 - ay0 + 1, 0);
    x0[L] = ax0; y0[L] = ay0; nxl[L] = nx;
    cb[L] = cnt; cnt += nx * ny;
  }
  int C = min(cnt, MAXC);

  for (int t = tid; t < C; t += 256) {
    int L = (t >= cb[2]) ? 2 : (t >= cb[1]) ? 1 : 0;
    int r = t - cb[L];
    int ix = r % nxl[L], iy = r / nxl[L];
    int px = x0[L] + ix, py = y0[L] + iy;
    float ax = (px + 0.5f) * ss[L], ay = (py + 0.5f) * ss[L];
    float al = -3e38f, iou = 0.f; int n = 0x7fffffff;
    if (ax > g.x && ay > g.y && ax < g.z && ay < g.w) {   // exact strict in_gts recheck
      n = nb[L] + py * Ws[L] + px;
      iou = iou_xyxy(pbox[(size_t)b * NANCH + n], g);
      int HW = (L == 0) ? 6400 : (L == 1) ? 1600 : 400;
      const float* p = lvl_ptr(p0, p1, p2, L);
      float z = p[(size_t)b * NCH * HW + (size_t)(RCH + gl) * HW + (py * Ws[L] + px)];
      float sg = 1.f / (1.f + __expf(-z));
      float i3 = iou * iou * iou;
      al = sqrtf(sg) * i3 * i3;
    }
    val[t] = al; idx[t] = n; cio[t] = iou;
  }
  __syncthreads();

  float mmax = -1.f;
  for (int k = 0; k < TOPKK; ++k) {
    float bv = -3e38f; int bn = 0x7fffffff, bs = 0;
    for (int t = tid; t < C; t += 256) {
      float v = val[t]; int n2 = idx[t];
      if (v > bv || (v == bv && n2 < bn)) { bv = v; bn = n2; bs = t; }
    }
    #pragma unroll
    for (int off = 32; off; off >>= 1) {
      float ov = __shfl_xor(bv, off);
      int   on = __shfl_xor(bn, off);
      int   os = __shfl_xor(bs, off);
      if (ov > bv || (ov == bv && on < bn)) { bv = ov; bn = on; bs = os; }
    }
    if ((tid & 63) == 0) { rv[tid >> 6] = bv; ri[tid >> 6] = bn; rs[tid >> 6] = bs; }
    __syncthreads();
    if (tid == 0) {
      #pragma unroll
      for (int w = 1; w < 4; ++w)
        if (rv[w] > bv || (rv[w] == bv && ri[w] < bn)) { bv = rv[w]; bn = ri[w]; bs = rs[w]; }
      if (bv >= 0.f) {          // valid <=> in_gts (align >= 0 for in-box)
        mmax = fmaxf(mmax, bv);
        // iou >= 0: float bits order-preserving; tie prefers smaller m (bigger 31-m)
        unsigned long long key = (1ULL << 62) |
                                 ((unsigned long long)__float_as_uint(cio[bs]) << 6) |
                                 (unsigned long long)(31 - m);
        atomicMax(&slots[(size_t)b * NANCH + bn], key);
        val[bs] = -3e38f;       // remove winner
        sdone[0] = 0;
      } else sdone[0] = 1;
    }
    __syncthreads();
    if (sdone[0]) break;
  }
  if (tid == 0) metric_max[b * MGT + m] = fmaxf(mmax, 1e-9f);
}

// --- K3: fg-anchor losses + last-block final combine -----------------------
__global__ __launch_bounds__(256) void k_final(
    const float* __restrict__ p0, const float* __restrict__ p1, const float* __restrict__ p2,
    const float4* __restrict__ pbox, const float* __restrict__ logz,
    const float* __restrict__ gtb, const int* __restrict__ gtl,
    const float* __restrict__ metric_max, const unsigned long long* __restrict__ slots,
    double* __restrict__ accum, int* __restrict__ counter, float* __restrict__ out) {
  int i = blockIdx.x * 256 + threadIdx.x;
  unsigned long long key = slots[i];
  float ts_p = 0.f, zc_p = 0.f, box_p = 0.f, dfl_p = 0.f;
  if (key) {
    int b = i / NANCH, n = i % NANCH;
    int m = 31 - (int)(key & 63ULL);
    float iou = __uint_as_float((unsigned int)((key >> 6) & 0xFFFFFFFFULL));
    AInfo A = anchor_of(n);
    float4 g = ((const float4*)gtb)[b * MGT + m];
    int gl = min(max(gtl[b * MGT + m], 0), NCLS - 1);
    const float* p = lvl_ptr(p0, p1, p2, A.lvl);
    size_t base = (size_t)b * NCH * A.HW + A.pos;

    float z = p[base + (size_t)(RCH + gl) * A.HW];
    float sg = 1.f / (1.f + __expf(-z));
    float i3 = iou * iou * iou;
    float align = sqrtf(sg) * i3 * i3;
    float mm = metric_max[b * MGT + m];
    float score = fminf(fmaxf(align / mm * iou, 0.f), 1.f);

    ts_p = score;
    zc_p = z * score;

    float4 pb = pbox[i];
    float ciou = ciou_xyxy(pb, g);
    box_p = (1.f - ciou) * score;

    float4 lz4 = ((const float4*)logz)[i];
    float inv_s = 1.f / A.s;
    float targ0 = (A.ax - g.x) * inv_s;
    float targ1 = (A.ay - g.y) * inv_s;
    float targ2 = (g.z - A.ax) * inv_s;
    float targ3 = (g.w - A.ay) * inv_s;
    float dfl = 0.f;
    #pragma unroll
    for (int sd = 0; sd < 4; ++sd) {
      float tg = sd == 0 ? targ0 : sd == 1 ? targ1 : sd == 2 ? targ2 : targ3;
      float lZ = sd == 0 ? lz4.x : sd == 1 ? lz4.y : sd == 2 ? lz4.z : lz4.w;
      float t = fminf(fmaxf(tg, 0.f), 15.f);
      int left = (int)floorf(t);
      int right = min(left + 1, 15);
      float wl, wr;
      if (right == left) { wl = 1.f; wr = 0.f; }
      else               { wl = (float)right - t; wr = t - (float)left; }
      float zl = p[base + (size_t)(sd * 16 + left)  * A.HW];
      float zr = p[base + (size_t)(sd * 16 + right) * A.HW];
      dfl += wl * (lZ - zl) + wr * (lZ - zr);
    }
    dfl_p = dfl * score;
  }
  float s;
  s = block_sum256(ts_p);  if (threadIdx.x == 0 && s != 0.f) atomicAdd(&accum[4], (double)s);
  s = block_sum256(zc_p);  if (threadIdx.x == 0 && s != 0.f) atomicAdd(&accum[1], (double)s);
  s = block_sum256(box_p); if (threadIdx.x == 0 && s != 0.f) atomicAdd(&accum[2], (double)s);
  s = block_sum256(dfl_p); if (threadIdx.x == 0 && s != 0.f) atomicAdd(&accum[3], (double)s);

  // last-finishing block computes the final scalar (replaces k_out launch)
  __threadfence();
  __shared__ int last;
  if (threadIdx.x == 0) last = (atomicAdd(counter, 1) == FINB - 1);
  __syncthreads();
  if (last && threadIdx.x == 0) {
    // device-scope atomic reads (plain loads could hit a stale per-XCD L2 line)
    double a0 = atomicAdd(&accum[0], 0.0);
    double a1 = atomicAdd(&accum[1], 0.0);
    double a2 = atomicAdd(&accum[2], 0.0);
    double a3 = atomicAdd(&accum[3], 0.0);
    double a4 = atomicAdd(&accum[4], 0.0);
    double ts = fmax(a4, 1.0);
    out[0] = (float)(7.5 * a2 / ts + 0.5 * (a0 - a1) / ts + 1.5 * a3 / ts);
  }
}

extern "C" void kernel_launch(void* const* d_in, const int* in_sizes, int n_in,
                              void* d_out, int out_size, void* d_ws, size_t ws_size,
                              hipStream_t stream) {
  const float* p0  = (const float*)d_in[0];
  const float* p1  = (const float*)d_in[1];
  const float* p2  = (const float*)d_in[2];
  const float* gtb = (const float*)d_in[3];
  const int*   gtl = (const int*)d_in[4];
  float* out = (float*)d_out;

  // Workspace layout (bytes, non-overlapping, aligned):
  //   accum      @ 0        : 8 * 8           = 64
  //   counter    @ 64       : 4 (pad to 16)
  //   metric_max @ 80       : 512 * 4         = 2048    (ends 2128)
  //   pbox/pboxf @ 2128     : 134400 * 16     = 2150400 (ends 2152528)  [2128 % 16 == 0]
  //   logz       @ 2152528  : 134400 * 16     = 2150400 (ends 4302928)  [% 16 == 0]
  //   slots      @ 4302928  : 134400 * 8      = 1075200 (ends 5378128)  [% 8 == 0]
  char* ws = (char*)d_ws;
  double* accum      = (double*)ws;
  int*    counter    = (int*)(ws + 64);
  float*  metric_max = (float*)(ws + 80);
  float*  pboxf      = (float*)(ws + 2128);
  float4* pbox       = (float4*)(ws + 2128);
  float*  logz       = (float*)(ws + 2152528);
  unsigned long long* slots = (unsigned long long*)(ws + 4302928);

  k_pre<<<PBLK, 256, 0, stream>>>(p0, p1, p2, pboxf, logz, slots, accum, counter);
  k_mid<<<TKB + BCEB, 256, 0, stream>>>(p0, p1, p2, pbox, gtb, gtl, metric_max, slots, accum);
  k_final<<<FINB, 256, 0, stream>>>(p0, p1, p2, pbox, logz, gtb, gtl,
                                    metric_max, slots, accum, counter, out);
}

// Round 8
// 146.975 us; speedup vs baseline: 1.3168x; 1.3168x over previous
//
#include <hip/hip_runtime.h>

#define BATCH 16
#define NANCH 8400
#define MGT 32
#define NCLS 80
#define RCH 64
#define NCH 144
#define TOPKK 10
#define MAXC 576    // max in-box candidate cells: <=19^2 + 11^2 + 7^2 = 531
#define PBLK 2100   // pbox blocks: 525 * 4 sides
#define TKB 512     // topk blocks
#define BCEB 2625   // bce blocks
#define FINB 525    // final blocks

struct AInfo { int lvl, pos, W, HW; float s, ax, ay; };

__device__ __forceinline__ AInfo anchor_of(int n) {
  AInfo a;
  if (n < 6400)      { a.lvl = 0; a.pos = n;        a.W = 80; a.HW = 6400; a.s = 8.f;  }
  else if (n < 8000) { a.lvl = 1; a.pos = n - 6400; a.W = 40; a.HW = 1600; a.s = 16.f; }
  else               { a.lvl = 2; a.pos = n - 8000; a.W = 20; a.HW = 400;  a.s = 32.f; }
  int px = a.pos % a.W, py = a.pos / a.W;
  a.ax = (px + 0.5f) * a.s;
  a.ay = (py + 0.5f) * a.s;
  return a;
}

__device__ __forceinline__ const float* lvl_ptr(const float* p0, const float* p1,
                                                const float* p2, int lvl) {
  return lvl == 0 ? p0 : (lvl == 1 ? p1 : p2);
}

__device__ __forceinline__ float iou_xyxy(float4 a, float4 b) {
  float ix = fmaxf(fminf(a.z, b.z) - fmaxf(a.x, b.x), 0.f);
  float iy = fmaxf(fminf(a.w, b.w) - fmaxf(a.y, b.y), 0.f);
  float inter = ix * iy;
  float w1 = fmaxf(a.z - a.x, 0.f), h1 = fmaxf(a.w - a.y, 0.f);
  float w2 = fmaxf(b.z - b.x, 0.f), h2 = fmaxf(b.w - b.y, 0.f);
  float uni = w1 * h1 + w2 * h2 - inter + 1e-7f;
  return inter / uni;
}

__device__ __forceinline__ float ciou_xyxy(float4 a, float4 b) {
  const float eps = 1e-7f;
  float ix = fmaxf(fminf(a.z, b.z) - fmaxf(a.x, b.x), 0.f);
  float iy = fmaxf(fminf(a.w, b.w) - fmaxf(a.y, b.y), 0.f);
  float inter = ix * iy;
  float w1 = fmaxf(a.z - a.x, 0.f), h1 = fmaxf(a.w - a.y, 0.f);
  float w2 = fmaxf(b.z - b.x, 0.f), h2 = fmaxf(b.w - b.y, 0.f);
  float uni = w1 * h1 + w2 * h2 - inter + eps;
  float iou = inter / uni;
  float cx1 = (a.x + a.z) * 0.5f, cy1 = (a.y + a.w) * 0.5f;
  float cx2 = (b.x + b.z) * 0.5f, cy2 = (b.y + b.w) * 0.5f;
  float rho2 = (cx2 - cx1) * (cx2 - cx1) + (cy2 - cy1) * (cy2 - cy1);
  float cw = fmaxf(a.z, b.z) - fminf(a.x, b.x);
  float ch = fmaxf(a.w, b.w) - fminf(a.y, b.y);
  float c2 = cw * cw + ch * ch + eps;
  const float kpi = 4.f / (float)(M_PI * M_PI);
  float dat = atanf(w2 / (h2 + eps)) - atanf(w1 / (h1 + eps));
  float v = kpi * dat * dat;
  float alpha = v / (1.f - iou + v + eps);
  return iou - (rho2 / c2 + alpha * v);
}

__device__ __forceinline__ float block_sum256(float v) {
  __shared__ float sm[4];
  #pragma unroll
  for (int off = 32; off; off >>= 1) v += __shfl_xor(v, off);
  __syncthreads();
  if ((threadIdx.x & 63) == 0) sm[threadIdx.x >> 6] = v;
  __syncthreads();
  return (threadIdx.x == 0) ? (sm[0] + sm[1] + sm[2] + sm[3]) : 0.f;
}

// --- K1: box decode + logZ cache + slots/accum init ------------------------
__global__ __launch_bounds__(256) void k_pre(
    const float* __restrict__ p0, const float* __restrict__ p1, const float* __restrict__ p2,
    float* __restrict__ pboxf, float* __restrict__ logz,
    unsigned long long* __restrict__ slots, double* __restrict__ accum) {
  int blk = blockIdx.x, tid = threadIdx.x;
  if (blk == 0 && tid < 8) accum[tid] = 0.0;
  // one thread per (anchor, side)
  int q = blk & 3;
  int i = (blk >> 2) * 256 + tid;            // 0 .. 134399
  int b = i / NANCH, n = i % NANCH;
  AInfo A = anchor_of(n);
  const float* p = lvl_ptr(p0, p1, p2, A.lvl);
  size_t base = (size_t)b * NCH * A.HW + A.pos;

  float z[16]; float zm = -1e30f;
  #pragma unroll
  for (int j = 0; j < 16; ++j) {
    z[j] = p[base + (size_t)(q * 16 + j) * A.HW];
    zm = fmaxf(zm, z[j]);
  }
  float se = 0.f, ae = 0.f;
  #pragma unroll
  for (int j = 0; j < 16; ++j) {
    float e = __expf(z[j] - zm);
    se += e; ae += e * (float)j;
  }
  float d = ae / se * A.s;
  float val = (q == 0) ? A.ax - d : (q == 1) ? A.ay - d : (q == 2) ? A.ax + d : A.ay + d;
  pboxf[(size_t)i * 4 + q] = val;
  logz[(size_t)i * 4 + q] = zm + __logf(se);   // log-softmax denominator (raw logits)
  if (q == 0) slots[i] = 0ULL;
}

// --- K2: topk (512 blocks) + BCE partial-store stream (2625 blocks) --------
__global__ __launch_bounds__(256) void k_mid(
    const float* __restrict__ p0, const float* __restrict__ p1, const float* __restrict__ p2,
    const float4* __restrict__ pbox, const float* __restrict__ gtb, const int* __restrict__ gtl,
    float* __restrict__ metric_max, unsigned long long* __restrict__ slots,
    float* __restrict__ bce_part) {
  __shared__ float val[MAXC];
  __shared__ int   idx[MAXC];
  __shared__ float cio[MAXC];
  __shared__ float rv[4];
  __shared__ int   ri[4], rs[4], sdone[1];
  int blk = blockIdx.x, tid = threadIdx.x;

  if (blk >= TKB) {
    // --- BCE base term: contiguous float4 stream, plain per-block partials ---
    int r = blk - TKB;                       // 0 .. 2624
    int i = r * 256 + tid;                   // 0 .. 671999
    float lb = 0.f;
    #pragma unroll
    for (int j = 0; j < 4; ++j) {
      int u = i + j * 672000;                // < 2688000
      int b = u / 168000;
      int rr = u % 168000;
      const float4* src;
      if (rr < 128000)      src = (const float4*)p0 + ((size_t)(b * NCH + RCH) * 1600 + rr);
      else if (rr < 160000) src = (const float4*)p1 + ((size_t)(b * NCH + RCH) * 400 + (rr - 128000));
      else                  src = (const float4*)p2 + ((size_t)(b * NCH + RCH) * 100 + (rr - 160000));
      float4 z4 = *src;
      lb += fmaxf(z4.x, 0.f) + __logf(1.f + __expf(-fabsf(z4.x)));
      lb += fmaxf(z4.y, 0.f) + __logf(1.f + __expf(-fabsf(z4.y)));
      lb += fmaxf(z4.z, 0.f) + __logf(1.f + __expf(-fabsf(z4.z)));
      lb += fmaxf(z4.w, 0.f) + __logf(1.f + __expf(-fabsf(z4.w)));
    }
    float tot = block_sum256(lb);
    if (tid == 0) bce_part[r] = tot;         // plain store, no device atomic
    return;
  }

  // --- topk for one (b, gt) ---
  int b = blk >> 5, m = blk & 31;
  float4 g = ((const float4*)gtb)[b * MGT + m];
  int gl = min(max(gtl[b * MGT + m], 0), NCLS - 1);

  const int   Ws[3] = {80, 40, 20};
  const float ss[3] = {8.f, 16.f, 32.f};
  const int   nb[3] = {0, 6400, 8000};
  int x0[3], y0[3], nxl[3], cb[3];
  int cnt = 0;
  #pragma unroll
  for (int L = 0; L < 3; ++L) {
    float s = ss[L]; int W = Ws[L];
    int ax0 = max((int)floorf(g.x / s - 0.5f), 0);        // widened 1 low side
    int ax1 = min((int)ceilf (g.z / s - 0.5f), W - 1);    // widened 1 high side
    int ay0 = max((int)floorf(g.y / s - 0.5f), 0);
    int ay1 = min((int)ceilf (g.w / s - 0.5f), W - 1);
    int nx = max(ax1 - ax0 + 1, 0);
    int ny = max(ay1 - ay0 + 1, 0);
    x0[L] = ax0; y0[L] = ay0; nxl[L] = nx;
    cb[L] = cnt; cnt += nx * ny;
  }
  int C = min(cnt, MAXC);

  for (int t = tid; t < C; t += 256) {
    int L = (t >= cb[2]) ? 2 : (t >= cb[1]) ? 1 : 0;
    int r = t - cb[L];
    int ix = r % nxl[L], iy = r / nxl[L];
    int px = x0[L] + ix, py = y0[L] + iy;
    float ax = (px + 0.5f) * ss[L], ay = (py + 0.5f) * ss[L];
    float al = -3e38f, iou = 0.f; int n = 0x7fffffff;
    if (ax > g.x && ay > g.y && ax < g.z && ay < g.w) {   // exact strict in_gts recheck
      n = nb[L] + py * Ws[L] + px;
      iou = iou_xyxy(pbox[(size_t)b * NANCH + n], g);
      int HW = (L == 0) ? 6400 : (L == 1) ? 1600 : 400;
      const float* p = lvl_ptr(p0, p1, p2, L);
      float z = p[(size_t)b * NCH * HW + (size_t)(RCH + gl) * HW + (py * Ws[L] + px)];
      float sg = 1.f / (1.f + __expf(-z));
      float i3 = iou * iou * iou;
      al = sqrtf(sg) * i3 * i3;
    }
    val[t] = al; idx[t] = n; cio[t] = iou;
  }
  __syncthreads();

  float mmax = -1.f;
  for (int k = 0; k < TOPKK; ++k) {
    float bv = -3e38f; int bn = 0x7fffffff, bs = 0;
    for (int t = tid; t < C; t += 256) {
      float v = val[t]; int n2 = idx[t];
      if (v > bv || (v == bv && n2 < bn)) { bv = v; bn = n2; bs = t; }
    }
    #pragma unroll
    for (int off = 32; off; off >>= 1) {
      float ov = __shfl_xor(bv, off);
      int   on = __shfl_xor(bn, off);
      int   os = __shfl_xor(bs, off);
      if (ov > bv || (ov == bv && on < bn)) { bv = ov; bn = on; bs = os; }
    }
    if ((tid & 63) == 0) { rv[tid >> 6] = bv; ri[tid >> 6] = bn; rs[tid >> 6] = bs; }
    __syncthreads();
    if (tid == 0) {
      #pragma unroll
      for (int w = 1; w < 4; ++w)
        if (rv[w] > bv || (rv[w] == bv && ri[w] < bn)) { bv = rv[w]; bn = ri[w]; bs = rs[w]; }
      if (bv >= 0.f) {          // valid <=> in_gts (align >= 0 for in-box)
        mmax = fmaxf(mmax, bv);
        // iou >= 0: float bits order-preserving; tie prefers smaller m (bigger 31-m)
        unsigned long long key = (1ULL << 62) |
                                 ((unsigned long long)__float_as_uint(cio[bs]) << 6) |
                                 (unsigned long long)(31 - m);
        atomicMax(&slots[(size_t)b * NANCH + bn], key);
        val[bs] = -3e38f;       // remove winner
        sdone[0] = 0;
      } else sdone[0] = 1;
    }
    __syncthreads();
    if (sdone[0]) break;
  }
  if (tid == 0) metric_max[b * MGT + m] = fmaxf(mmax, 1e-9f);
}

// --- K3: fg-anchor losses (no fence, no combine tail) ----------------------
__global__ __launch_bounds__(256) void k_final(
    const float* __restrict__ p0, const float* __restrict__ p1, const float* __restrict__ p2,
    const float4* __restrict__ pbox, const float* __restrict__ logz,
    const float* __restrict__ gtb, const int* __restrict__ gtl,
    const float* __restrict__ metric_max, const unsigned long long* __restrict__ slots,
    double* __restrict__ accum) {
  int i = blockIdx.x * 256 + threadIdx.x;
  unsigned long long key = slots[i];
  float ts_p = 0.f, zc_p = 0.f, box_p = 0.f, dfl_p = 0.f;
  if (key) {
    int b = i / NANCH, n = i % NANCH;
    int m = 31 - (int)(key & 63ULL);
    float iou = __uint_as_float((unsigned int)((key >> 6) & 0xFFFFFFFFULL));
    AInfo A = anchor_of(n);
    float4 g = ((const float4*)gtb)[b * MGT + m];
    int gl = min(max(gtl[b * MGT + m], 0), NCLS - 1);
    const float* p = lvl_ptr(p0, p1, p2, A.lvl);
    size_t base = (size_t)b * NCH * A.HW + A.pos;

    float z = p[base + (size_t)(RCH + gl) * A.HW];
    float sg = 1.f / (1.f + __expf(-z));
    float i3 = iou * iou * iou;
    float align = sqrtf(sg) * i3 * i3;
    float mm = metric_max[b * MGT + m];
    float score = fminf(fmaxf(align / mm * iou, 0.f), 1.f);

    ts_p = score;
    zc_p = z * score;

    float4 pb = pbox[i];
    float ciou = ciou_xyxy(pb, g);
    box_p = (1.f - ciou) * score;

    float4 lz4 = ((const float4*)logz)[i];
    float inv_s = 1.f / A.s;
    float targ0 = (A.ax - g.x) * inv_s;
    float targ1 = (A.ay - g.y) * inv_s;
    float targ2 = (g.z - A.ax) * inv_s;
    float targ3 = (g.w - A.ay) * inv_s;
    float dfl = 0.f;
    #pragma unroll
    for (int sd = 0; sd < 4; ++sd) {
      float tg = sd == 0 ? targ0 : sd == 1 ? targ1 : sd == 2 ? targ2 : targ3;
      float lZ = sd == 0 ? lz4.x : sd == 1 ? lz4.y : sd == 2 ? lz4.z : lz4.w;
      float t = fminf(fmaxf(tg, 0.f), 15.f);
      int left = (int)floorf(t);
      int right = min(left + 1, 15);
      float wl, wr;
      if (right == left) { wl = 1.f; wr = 0.f; }
      else               { wl = (float)right - t; wr = t - (float)left; }
      float zl = p[base + (size_t)(sd * 16 + left)  * A.HW];
      float zr = p[base + (size_t)(sd * 16 + right) * A.HW];
      dfl += wl * (lZ - zl) + wr * (lZ - zr);
    }
    dfl_p = dfl * score;
  }
  float s;
  s = block_sum256(ts_p);  if (threadIdx.x == 0 && s != 0.f) atomicAdd(&accum[4], (double)s);
  s = block_sum256(zc_p);  if (threadIdx.x == 0 && s != 0.f) atomicAdd(&accum[1], (double)s);
  s = block_sum256(box_p); if (threadIdx.x == 0 && s != 0.f) atomicAdd(&accum[2], (double)s);
  s = block_sum256(dfl_p); if (threadIdx.x == 0 && s != 0.f) atomicAdd(&accum[3], (double)s);
}

// --- K4: combine (sums bce partials too) -----------------------------------
__global__ void k_out(const double* __restrict__ accum, const float* __restrict__ bce_part,
                      float* __restrict__ out) {
  int tid = threadIdx.x;
  float s = 0.f;
  for (int t = tid; t < BCEB; t += 256) s += bce_part[t];
  s = block_sum256(s);
  if (tid == 0) {
    double ts = fmax(accum[4], 1.0);
    double loss = 7.5 * accum[2] / ts +
                  0.5 * ((double)s - accum[1]) / ts +
                  1.5 * accum[3] / ts;
    out[0] = (float)loss;
  }
}

extern "C" void kernel_launch(void* const* d_in, const int* in_sizes, int n_in,
                              void* d_out, int out_size, void* d_ws, size_t ws_size,
                              hipStream_t stream) {
  const float* p0  = (const float*)d_in[0];
  const float* p1  = (const float*)d_in[1];
  const float* p2  = (const float*)d_in[2];
  const float* gtb = (const float*)d_in[3];
  const int*   gtl = (const int*)d_in[4];
  float* out = (float*)d_out;

  // Workspace layout (bytes, non-overlapping, aligned):
  //   accum      @ 0        : 8 * 8       = 64
  //   metric_max @ 64       : 512 * 4     = 2048    (ends 2112)
  //   bce_part   @ 2112     : 2625 * 4    = 10500   (ends 12612; pad to 12624)
  //   pbox/pboxf @ 12624    : 134400 * 16 = 2150400 (ends 2163024)  [% 16 == 0]
  //   logz       @ 2163024  : 134400 * 16 = 2150400 (ends 4313424)  [% 16 == 0]
  //   slots      @ 4313424  : 134400 * 8  = 1075200 (ends 5388624)  [% 8 == 0]
  char* ws = (char*)d_ws;
  double* accum      = (double*)ws;
  float*  metric_max = (float*)(ws + 64);
  float*  bce_part   = (float*)(ws + 2112);
  float*  pboxf      = (float*)(ws + 12624);
  float4* pbox       = (float4*)(ws + 12624);
  float*  logz       = (float*)(ws + 2163024);
  unsigned long long* slots = (unsigned long long*)(ws + 4313424);

  k_pre<<<PBLK, 256, 0, stream>>>(p0, p1, p2, pboxf, logz, slots, accum);
  k_mid<<<TKB + BCEB, 256, 0, stream>>>(p0, p1, p2, pbox, gtb, gtl, metric_max, slots, bce_part);
  k_final<<<FINB, 256, 0, stream>>>(p0, p1, p2, pbox, logz, gtb, gtl,
                                    metric_max, slots, accum);
  k_out<<<1, 256, 0, stream>>>(accum, bce_part, out);
}

// Round 9
// 135.291 us; speedup vs baseline: 1.4305x; 1.0864x over previous
//
#include <hip/hip_runtime.h>

#define BATCH 16
#define NANCH 8400
#define MGT 32
#define NCLS 80
#define RCH 64
#define NCH 144
#define TOPKK 10
#define MAXC 576    // max in-box candidate cells: <=19^2 + 11^2 + 7^2 = 531
#define TKB 512     // topk blocks        [0, 512)
#define DECB 2100   // decode blocks      [512, 2612)
#define BCEB 2625   // bce blocks         [2612, 5237)
#define TOTB (TKB + DECB + BCEB)
#define FINB 525    // final blocks

struct AInfo { int lvl, pos, W, HW; float s, ax, ay; };

__device__ __forceinline__ AInfo anchor_of(int n) {
  AInfo a;
  if (n < 6400)      { a.lvl = 0; a.pos = n;        a.W = 80; a.HW = 6400; a.s = 8.f;  }
  else if (n < 8000) { a.lvl = 1; a.pos = n - 6400; a.W = 40; a.HW = 1600; a.s = 16.f; }
  else               { a.lvl = 2; a.pos = n - 8000; a.W = 20; a.HW = 400;  a.s = 32.f; }
  int px = a.pos % a.W, py = a.pos / a.W;
  a.ax = (px + 0.5f) * a.s;
  a.ay = (py + 0.5f) * a.s;
  return a;
}

__device__ __forceinline__ const float* lvl_ptr(const float* p0, const float* p1,
                                                const float* p2, int lvl) {
  return lvl == 0 ? p0 : (lvl == 1 ? p1 : p2);
}

// Identical op order to the k_dec per-side path -> bit-identical boxes.
__device__ __forceinline__ float4 decode_box(const float* __restrict__ p, size_t chbase,
                                             int HW, float s, float ax, float ay) {
  float d[4];
  #pragma unroll
  for (int q = 0; q < 4; ++q) {
    float z[16]; float zm = -1e30f;
    #pragma unroll
    for (int j = 0; j < 16; ++j) {
      z[j] = p[chbase + (size_t)(q * 16 + j) * HW];
      zm = fmaxf(zm, z[j]);
    }
    float se = 0.f, ae = 0.f;
    #pragma unroll
    for (int j = 0; j < 16; ++j) {
      float e = __expf(z[j] - zm);
      se += e; ae += e * (float)j;
    }
    d[q] = ae / se * s;
  }
  return make_float4(ax - d[0], ay - d[1], ax + d[2], ay + d[3]);
}

__device__ __forceinline__ float iou_xyxy(float4 a, float4 b) {
  float ix = fmaxf(fminf(a.z, b.z) - fmaxf(a.x, b.x), 0.f);
  float iy = fmaxf(fminf(a.w, b.w) - fmaxf(a.y, b.y), 0.f);
  float inter = ix * iy;
  float w1 = fmaxf(a.z - a.x, 0.f), h1 = fmaxf(a.w - a.y, 0.f);
  float w2 = fmaxf(b.z - b.x, 0.f), h2 = fmaxf(b.w - b.y, 0.f);
  float uni = w1 * h1 + w2 * h2 - inter + 1e-7f;
  return inter / uni;
}

__device__ __forceinline__ float ciou_xyxy(float4 a, float4 b) {
  const float eps = 1e-7f;
  float ix = fmaxf(fminf(a.z, b.z) - fmaxf(a.x, b.x), 0.f);
  float iy = fmaxf(fminf(a.w, b.w) - fmaxf(a.y, b.y), 0.f);
  float inter = ix * iy;
  float w1 = fmaxf(a.z - a.x, 0.f), h1 = fmaxf(a.w - a.y, 0.f);
  float w2 = fmaxf(b.z - b.x, 0.f), h2 = fmaxf(b.w - b.y, 0.f);
  float uni = w1 * h1 + w2 * h2 - inter + eps;
  float iou = inter / uni;
  float cx1 = (a.x + a.z) * 0.5f, cy1 = (a.y + a.w) * 0.5f;
  float cx2 = (b.x + b.z) * 0.5f, cy2 = (b.y + b.w) * 0.5f;
  float rho2 = (cx2 - cx1) * (cx2 - cx1) + (cy2 - cy1) * (cy2 - cy1);
  float cw = fmaxf(a.z, b.z) - fminf(a.x, b.x);
  float ch = fmaxf(a.w, b.w) - fminf(a.y, b.y);
  float c2 = cw * cw + ch * ch + eps;
  const float kpi = 4.f / (float)(M_PI * M_PI);
  float dat = atanf(w2 / (h2 + eps)) - atanf(w1 / (h1 + eps));
  float v = kpi * dat * dat;
  float alpha = v / (1.f - iou + v + eps);
  return iou - (rho2 / c2 + alpha * v);
}

__device__ __forceinline__ float block_sum256(float v) {
  __shared__ float sm[4];
  #pragma unroll
  for (int off = 32; off; off >>= 1) v += __shfl_xor(v, off);
  __syncthreads();
  if ((threadIdx.x & 63) == 0) sm[threadIdx.x >> 6] = v;
  __syncthreads();
  return (threadIdx.x == 0) ? (sm[0] + sm[1] + sm[2] + sm[3]) : 0.f;
}

__device__ __forceinline__ double block_sum256d(double v) {
  __shared__ double smd[4];
  #pragma unroll
  for (int off = 32; off; off >>= 1) v += __shfl_xor(v, off);
  __syncthreads();
  if ((threadIdx.x & 63) == 0) smd[threadIdx.x >> 6] = v;
  __syncthreads();
  return (threadIdx.x == 0) ? (smd[0] + smd[1] + smd[2] + smd[3]) : 0.0;
}

// --- K1: topk (recomputes candidate boxes) || box decode || BCE stream ------
__global__ __launch_bounds__(256) void k_one(
    const float* __restrict__ p0, const float* __restrict__ p1, const float* __restrict__ p2,
    const float* __restrict__ gtb, const int* __restrict__ gtl,
    float* __restrict__ pboxf, float* __restrict__ logz,
    float* __restrict__ metric_max, unsigned long long* __restrict__ slots,
    float* __restrict__ bce_part) {
  __shared__ float val[MAXC];
  __shared__ int   idx[MAXC];
  __shared__ float cio[MAXC];
  __shared__ float rv[4];
  __shared__ int   ri[4], rs[4], sdone[1];
  int blk = blockIdx.x, tid = threadIdx.x;

  if (blk >= TKB + DECB) {
    // --- BCE base term: contiguous float4 stream, plain per-block partials ---
    int r = blk - (TKB + DECB);              // 0 .. 2624
    int i = r * 256 + tid;                   // 0 .. 671999
    float lb = 0.f;
    #pragma unroll
    for (int j = 0; j < 4; ++j) {
      int u = i + j * 672000;                // < 2688000
      int b = u / 168000;
      int rr = u % 168000;
      const float4* src;
      if (rr < 128000)      src = (const float4*)p0 + ((size_t)(b * NCH + RCH) * 1600 + rr);
      else if (rr < 160000) src = (const float4*)p1 + ((size_t)(b * NCH + RCH) * 400 + (rr - 128000));
      else                  src = (const float4*)p2 + ((size_t)(b * NCH + RCH) * 100 + (rr - 160000));
      float4 z4 = *src;
      lb += fmaxf(z4.x, 0.f) + __logf(1.f + __expf(-fabsf(z4.x)));
      lb += fmaxf(z4.y, 0.f) + __logf(1.f + __expf(-fabsf(z4.y)));
      lb += fmaxf(z4.z, 0.f) + __logf(1.f + __expf(-fabsf(z4.z)));
      lb += fmaxf(z4.w, 0.f) + __logf(1.f + __expf(-fabsf(z4.w)));
    }
    float tot = block_sum256(lb);
    if (tid == 0) bce_part[r] = tot;
    return;
  }

  if (blk >= TKB) {
    // --- box decode for k_final: one thread per (anchor, side) ---
    int db = blk - TKB;
    int q = db & 3;
    int i = (db >> 2) * 256 + tid;           // 0 .. 134399
    int b = i / NANCH, n = i % NANCH;
    AInfo A = anchor_of(n);
    const float* p = lvl_ptr(p0, p1, p2, A.lvl);
    size_t base = (size_t)b * NCH * A.HW + A.pos;

    float z[16]; float zm = -1e30f;
    #pragma unroll
    for (int j = 0; j < 16; ++j) {
      z[j] = p[base + (size_t)(q * 16 + j) * A.HW];
      zm = fmaxf(zm, z[j]);
    }
    float se = 0.f, ae = 0.f;
    #pragma unroll
    for (int j = 0; j < 16; ++j) {
      float e = __expf(z[j] - zm);
      se += e; ae += e * (float)j;
    }
    float d = ae / se * A.s;
    float v = (q == 0) ? A.ax - d : (q == 1) ? A.ay - d : (q == 2) ? A.ax + d : A.ay + d;
    pboxf[(size_t)i * 4 + q] = v;
    logz[(size_t)i * 4 + q] = zm + __logf(se);
    return;
  }

  // --- topk for one (b, gt): enumerate in-box candidates, decode locally ---
  int b = blk >> 5, m = blk & 31;
  float4 g = ((const float4*)gtb)[b * MGT + m];
  int gl = min(max(gtl[b * MGT + m], 0), NCLS - 1);

  const int   Ws[3] = {80, 40, 20};
  const float ss[3] = {8.f, 16.f, 32.f};
  const int   nb[3] = {0, 6400, 8000};
  int x0[3], y0[3], nxl[3], cb[3];
  int cnt = 0;
  #pragma unroll
  for (int L = 0; L < 3; ++L) {
    float s = ss[L]; int W = Ws[L];
    int ax0 = max((int)floorf(g.x / s - 0.5f), 0);        // widened 1 low side
    int ax1 = min((int)ceilf (g.z / s - 0.5f), W - 1);    // widened 1 high side
    int ay0 = max((int)floorf(g.y / s - 0.5f), 0);
    int ay1 = min((int)ceilf (g.w / s - 0.5f), W - 1);
    int nx = max(ax1 - ax0 + 1, 0);
    int ny = max(ay1 - ay0 + 1, 0);
    x0[L] = ax0; y0[L] = ay0; nxl[L] = nx;
    cb[L] = cnt; cnt += nx * ny;
  }
  int C = min(cnt, MAXC);

  for (int t = tid; t < C; t += 256) {
    int L = (t >= cb[2]) ? 2 : (t >= cb[1]) ? 1 : 0;
    int r = t - cb[L];
    int ix = r % nxl[L], iy = r / nxl[L];
    int px = x0[L] + ix, py = y0[L] + iy;
    float ax = (px + 0.5f) * ss[L], ay = (py + 0.5f) * ss[L];
    float al = -3e38f, iou = 0.f; int n = 0x7fffffff;
    if (ax > g.x && ay > g.y && ax < g.z && ay < g.w) {   // exact strict in_gts
      int W = Ws[L];
      int HW = (L == 0) ? 6400 : (L == 1) ? 1600 : 400;
      int pos = py * W + px;
      n = nb[L] + pos;
      const float* p = lvl_ptr(p0, p1, p2, L);
      size_t chbase = (size_t)b * NCH * HW + pos;
      float4 pb = decode_box(p, chbase, HW, ss[L], ax, ay);  // bit-identical to k_dec
      iou = iou_xyxy(pb, g);
      float z = p[chbase + (size_t)(RCH + gl) * HW];
      float sg = 1.f / (1.f + __expf(-z));
      float i3 = iou * iou * iou;
      al = sqrtf(sg) * i3 * i3;
    }
    val[t] = al; idx[t] = n; cio[t] = iou;
  }
  __syncthreads();

  float mmax = -1.f;
  for (int k = 0; k < TOPKK; ++k) {
    float bv = -3e38f; int bn = 0x7fffffff, bs = 0;
    for (int t = tid; t < C; t += 256) {
      float v = val[t]; int n2 = idx[t];
      if (v > bv || (v == bv && n2 < bn)) { bv = v; bn = n2; bs = t; }
    }
    #pragma unroll
    for (int off = 32; off; off >>= 1) {
      float ov = __shfl_xor(bv, off);
      int   on = __shfl_xor(bn, off);
      int   os = __shfl_xor(bs, off);
      if (ov > bv || (ov == bv && on < bn)) { bv = ov; bn = on; bs = os; }
    }
    if ((tid & 63) == 0) { rv[tid >> 6] = bv; ri[tid >> 6] = bn; rs[tid >> 6] = bs; }
    __syncthreads();
    if (tid == 0) {
      #pragma unroll
      for (int w = 1; w < 4; ++w)
        if (rv[w] > bv || (rv[w] == bv && ri[w] < bn)) { bv = rv[w]; bn = ri[w]; bs = rs[w]; }
      if (bv >= 0.f) {          // valid <=> in_gts (align >= 0 for in-box)
        mmax = fmaxf(mmax, bv);
        // iou >= 0: float bits order-preserving; tie prefers smaller m (bigger 31-m)
        unsigned long long key = (1ULL << 62) |
                                 ((unsigned long long)__float_as_uint(cio[bs]) << 6) |
                                 (unsigned long long)(31 - m);
        atomicMax(&slots[(size_t)b * NANCH + bn], key);
        val[bs] = -3e38f;       // remove winner
        sdone[0] = 0;
      } else sdone[0] = 1;
    }
    __syncthreads();
    if (sdone[0]) break;
  }
  if (tid == 0) metric_max[b * MGT + m] = fmaxf(mmax, 1e-9f);
}

// --- K2: fg-anchor losses -> plain-store per-block partials (NO atomics) ---
__global__ __launch_bounds__(256) void k_fin(
    const float* __restrict__ p0, const float* __restrict__ p1, const float* __restrict__ p2,
    const float4* __restrict__ pbox, const float* __restrict__ logz,
    const float* __restrict__ gtb, const int* __restrict__ gtl,
    const float* __restrict__ metric_max, const unsigned long long* __restrict__ slots,
    float4* __restrict__ fin_part) {
  int i = blockIdx.x * 256 + threadIdx.x;
  unsigned long long key = slots[i];
  float ts_p = 0.f, zc_p = 0.f, box_p = 0.f, dfl_p = 0.f;
  if (key) {
    int b = i / NANCH, n = i % NANCH;
    int m = 31 - (int)(key & 63ULL);
    float iou = __uint_as_float((unsigned int)((key >> 6) & 0xFFFFFFFFULL));
    AInfo A = anchor_of(n);
    float4 g = ((const float4*)gtb)[b * MGT + m];
    int gl = min(max(gtl[b * MGT + m], 0), NCLS - 1);
    const float* p = lvl_ptr(p0, p1, p2, A.lvl);
    size_t base = (size_t)b * NCH * A.HW + A.pos;

    float z = p[base + (size_t)(RCH + gl) * A.HW];
    float sg = 1.f / (1.f + __expf(-z));
    float i3 = iou * iou * iou;
    float align = sqrtf(sg) * i3 * i3;
    float mm = metric_max[b * MGT + m];
    float score = fminf(fmaxf(align / mm * iou, 0.f), 1.f);

    ts_p = score;
    zc_p = z * score;

    float4 pb = pbox[i];
    float ciou = ciou_xyxy(pb, g);
    box_p = (1.f - ciou) * score;

    float4 lz4 = ((const float4*)logz)[i];
    float inv_s = 1.f / A.s;
    float targ0 = (A.ax - g.x) * inv_s;
    float targ1 = (A.ay - g.y) * inv_s;
    float targ2 = (g.z - A.ax) * inv_s;
    float targ3 = (g.w - A.ay) * inv_s;
    float dfl = 0.f;
    #pragma unroll
    for (int sd = 0; sd < 4; ++sd) {
      float tg = sd == 0 ? targ0 : sd == 1 ? targ1 : sd == 2 ? targ2 : targ3;
      float lZ = sd == 0 ? lz4.x : sd == 1 ? lz4.y : sd == 2 ? lz4.z : lz4.w;
      float t = fminf(fmaxf(tg, 0.f), 15.f);
      int left = (int)floorf(t);
      int right = min(left + 1, 15);
      float wl, wr;
      if (right == left) { wl = 1.f; wr = 0.f; }
      else               { wl = (float)right - t; wr = t - (float)left; }
      float zl = p[base + (size_t)(sd * 16 + left)  * A.HW];
      float zr = p[base + (size_t)(sd * 16 + right) * A.HW];
      dfl += wl * (lZ - zl) + wr * (lZ - zr);
    }
    dfl_p = dfl * score;
  }
  float s0 = block_sum256(box_p);
  float s1 = block_sum256(zc_p);
  float s2 = block_sum256(dfl_p);
  float s3 = block_sum256(ts_p);
  if (threadIdx.x == 0) fin_part[blockIdx.x] = make_float4(s0, s1, s2, s3);
}

// --- K3: combine all partials in f64 ---------------------------------------
__global__ void k_out(const float* __restrict__ bce_part, const float4* __restrict__ fin_part,
                      float* __restrict__ out) {
  int tid = threadIdx.x;
  double sb = 0.0, s0 = 0.0, s1 = 0.0, s2 = 0.0, s3 = 0.0;
  for (int t = tid; t < BCEB; t += 256) sb += (double)bce_part[t];
  for (int t = tid; t < FINB; t += 256) {
    float4 f = fin_part[t];
    s0 += (double)f.x; s1 += (double)f.y; s2 += (double)f.z; s3 += (double)f.w;
  }
  sb = block_sum256d(sb);
  s0 = block_sum256d(s0);
  s1 = block_sum256d(s1);
  s2 = block_sum256d(s2);
  s3 = block_sum256d(s3);
  if (tid == 0) {
    double ts = fmax(s3, 1.0);
    out[0] = (float)(7.5 * s0 / ts + 0.5 * (sb - s1) / ts + 1.5 * s2 / ts);
  }
}

extern "C" void kernel_launch(void* const* d_in, const int* in_sizes, int n_in,
                              void* d_out, int out_size, void* d_ws, size_t ws_size,
                              hipStream_t stream) {
  const float* p0  = (const float*)d_in[0];
  const float* p1  = (const float*)d_in[1];
  const float* p2  = (const float*)d_in[2];
  const float* gtb = (const float*)d_in[3];
  const int*   gtl = (const int*)d_in[4];
  float* out = (float*)d_out;

  // Workspace layout (bytes, non-overlapping, aligned):
  //   metric_max @ 0        : 512 * 4     = 2048
  //   bce_part   @ 2048     : 2625 * 4    = 10500   (ends 12548; pad to 12560)
  //   fin_part   @ 12560    : 525 * 16    = 8400    (ends 20960)  [% 16 == 0]
  //   pbox/pboxf @ 20960    : 134400 * 16 = 2150400 (ends 2171360) [% 16 == 0]
  //   logz       @ 2171360  : 134400 * 16 = 2150400 (ends 4321760) [% 16 == 0]
  //   slots      @ 4321760  : 134400 * 8  = 1075200 (ends 5396960) [% 8 == 0]
  char* ws = (char*)d_ws;
  float*  metric_max = (float*)ws;
  float*  bce_part   = (float*)(ws + 2048);
  float4* fin_part   = (float4*)(ws + 12560);
  float*  pboxf      = (float*)(ws + 20960);
  float4* pbox       = (float4*)(ws + 20960);
  float*  logz       = (float*)(ws + 2171360);
  unsigned long long* slots = (unsigned long long*)(ws + 4321760);

  hipMemsetAsync(slots, 0, (size_t)BATCH * NANCH * 8, stream);
  k_one<<<TOTB, 256, 0, stream>>>(p0, p1, p2, gtb, gtl, pboxf, logz,
                                  metric_max, slots, bce_part);
  k_fin<<<FINB, 256, 0, stream>>>(p0, p1, p2, pbox, logz, gtb, gtl,
                                  metric_max, slots, fin_part);
  k_out<<<1, 256, 0, stream>>>(bce_part, fin_part, out);
}